// Round 1
// baseline (206.961 us; speedup 1.0000x reference)
//
#include <hip/hip_runtime.h>

#define NT 8
#define NY 32
#define NX 32
#define NN 1024  // NY*NX

// Stencil coefficients of M = I + A for one node. c[(ry+1)*3+(rx+1)] is the
// coefficient toward target offset (ry,rx); zeroed when the TARGET node falls
// off-grid (matches reference `valid` masking on the column node).
__device__ __forceinline__ void node_coefs(const float* __restrict__ kap,
                                           const float* __restrict__ m,
                                           const float* __restrict__ H,
                                           const float* __restrict__ tau,
                                           int b, int node, int tc,
                                           int iy, int ix,
                                           float* c /*[9]*/, float& w) {
    const int base = node * NT + tc;                 // [.., node, t] layout, last dim NT
    const float kp  = kap[(b * NN) * NT + base];
    const float m1  = m[((b * 2 + 0) * NN) * NT + base];
    const float m2  = m[((b * 2 + 1) * NN) * NT + base];
    const float h11 = H[((b * 4 + 0) * NN) * NT + base];
    const float h12 = H[((b * 4 + 1) * NN) * NT + base];
    const float h22 = H[((b * 4 + 3) * NN) * NT + base];
    const float tv  = tau[(b * NN) * NT + base];
    w = 1.0f / (tv * tv);

    const float cxy = 0.5f * h12;
    const bool ym = iy > 0, yp = iy < NY - 1;
    const bool xm = ix > 0, xp = ix < NX - 1;

    c[4] = 1.0f + kp * kp + 2.0f * h11 + 2.0f * h22;
    c[0] = (ym && xm) ? -cxy               : 0.0f;
    c[1] =  ym        ? (-h22 - 0.5f * m2) : 0.0f;
    c[2] = (ym && xp) ?  cxy               : 0.0f;
    c[3] =  xm        ? (-h11 - 0.5f * m1) : 0.0f;
    c[5] =  xp        ? (-h11 + 0.5f * m1) : 0.0f;
    c[6] = (yp && xm) ?  cxy               : 0.0f;
    c[7] =  yp        ? (-h22 + 0.5f * m2) : 0.0f;
    c[8] = (yp && xp) ? -cxy               : 0.0f;
}

// Scatter-only kernel: output has already been zeroed by hipMemsetAsync.
// Each 64-lane group handles one (b, t, j) row-set and writes ONLY the
// <=25 D nonzeros, <=9 lower nonzeros, <=9 upper nonzeros.
//   D[t]       row j, col k=j+(dy,dx), |dy|,|dx|<=2 : sum_i M[i,j] w[i] M[i,k]
//   lower[t]   row j, col k=j+off_d  : -w_t[k] M_t[k,j]   (t>=1; L[0] stays 0)
//   upper[t-1] row j, col k=j+off_q  : -w_t[j] M_t[j,k]   (t>=1; U[7] stays 0)
__global__ __launch_bounds__(256) void spde_scatter(const float* __restrict__ kap,
                                                    const float* __restrict__ m,
                                                    const float* __restrict__ H,
                                                    const float* __restrict__ tau,
                                                    float* __restrict__ out) {
    __shared__ float sc[4][9][9];   // sc[w][d][r]: coef of node j_w+off_d toward offset r
    __shared__ float sw[4][9];      // w_t at node j_w+off_d (0 if off-grid)

    const int gb  = blockIdx.x;          // ((b*NT)+t)*256 + j4 ; j = j4*4 + wid
    const int j4  = gb & 255;
    const int bt  = gb >> 8;
    const int t   = bt & 7;
    const int b   = bt >> 3;
    const int wid  = threadIdx.x >> 6;   // which j this 64-lane group owns
    const int lane = threadIdx.x & 63;
    const int j  = j4 * 4 + wid;
    const int jy = j >> 5, jx = j & 31;

    if (lane < 9) {  // phase 0: stencil coefs of the 9 neighborhood nodes at time t
        const int ey = lane / 3 - 1, ex = lane % 3 - 1;
        const int iy = jy + ey, ix = jx + ex;
        float c[9];
        float w = 0.0f;
        if (iy >= 0 && iy < NY && ix >= 0 && ix < NX) {
            node_coefs(kap, m, H, tau, b, iy * NX + ix, t, iy, ix, c, w);
        } else {
            #pragma unroll
            for (int q = 0; q < 9; ++q) c[q] = 0.0f;
        }
        #pragma unroll
        for (int q = 0; q < 9; ++q) sc[wid][lane][q] = c[q];
        sw[wid][lane] = w;
    }
    __syncthreads();

    if (lane < 25) {                     // D nonzeros
        const int dy = lane / 5 - 2, dx = lane % 5 - 2;
        const int ky = jy + dy, kx = jx + dx;
        if (ky >= 0 && ky < NY && kx >= 0 && kx < NX) {
            float acc = 0.0f;
            #pragma unroll
            for (int d = 0; d < 9; ++d) {   // rows i = j + off_d
                const int ey = d / 3 - 1, ex = d % 3 - 1;
                const int r2y = dy - ey, r2x = dx - ex;
                if (r2y >= -1 && r2y <= 1 && r2x >= -1 && r2x <= 1) {
                    acc += sw[wid][d] * sc[wid][d][8 - d]
                                      * sc[wid][d][(r2y + 1) * 3 + (r2x + 1)];
                }
            }
            if (lane == 12 && t < NT - 1) {  // diagonal: + w_{t+1}[j]
                const float tv = tau[((size_t)b * NN + j) * NT + (t + 1)];
                acc += 1.0f / (tv * tv);
            }
            float* Drow = out + (((size_t)(b * 3 + 0) * NT + t) << 20) + ((size_t)j << 10);
            Drow[ky * NX + kx] = acc;
        }
    } else if (lane >= 32 && lane < 41) {  // lower[t] nonzeros (t>=1)
        if (t > 0) {
            const int d  = lane - 32;
            const int ey = d / 3 - 1, ex = d % 3 - 1;
            const int ky = jy + ey, kx = jx + ex;
            if (ky >= 0 && ky < NY && kx >= 0 && kx < NX) {
                float* Lrow = out + (((size_t)(b * 3 + 1) * NT + t) << 20) + ((size_t)j << 10);
                Lrow[ky * NX + kx] = -sw[wid][d] * sc[wid][d][8 - d];
            }
        }
    } else if (lane >= 48 && lane < 57) {  // upper[t-1] nonzeros (t>=1)
        if (t > 0) {
            const int q  = lane - 48;
            const int ey = q / 3 - 1, ex = q % 3 - 1;
            const int ky = jy + ey, kx = jx + ex;
            if (ky >= 0 && ky < NY && kx >= 0 && kx < NX) {
                float* Urow = out + (((size_t)(b * 3 + 2) * NT + (t - 1)) << 20) + ((size_t)j << 10);
                Urow[ky * NX + kx] = -sw[wid][4] * sc[wid][4][q];
            }
        }
    }
}

extern "C" void kernel_launch(void* const* d_in, const int* in_sizes, int n_in,
                              void* d_out, int out_size, void* d_ws, size_t ws_size,
                              hipStream_t stream) {
    (void)n_in; (void)d_ws; (void)ws_size;
    const float* kap = (const float*)d_in[0];  // [n_b,1,N,NT]
    const float* m   = (const float*)d_in[1];  // [n_b,2,N,NT]
    const float* H   = (const float*)d_in[2];  // [n_b,2,2,N,NT]
    const float* tau = (const float*)d_in[3];  // [n_b,1,N,NT]
    float* out = (float*)d_out;                // [n_b,3,NT,N,N]

    const int n_b = in_sizes[0] / (NN * NT);

    // Phase 1: zero the whole output via the vendor fill path
    // (measured 6.7 TB/s on this buffer in the current profile).
    hipMemsetAsync(d_out, 0, (size_t)out_size, stream);

    // Phase 2: scatter the ~43 nonzeros per (b,t,j) row-set.
    const int grid = n_b * NT * 256;           // 4 j's per 256-thread block
    spde_scatter<<<grid, 256, 0, stream>>>(kap, m, H, tau, out);
}

// Round 2
// 201.498 us; speedup vs baseline: 1.0271x; 1.0271x over previous
//
#include <hip/hip_runtime.h>

#define NT 8
#define NY 32
#define NX 32
#define NN 1024  // NY*NX

// Stencil coefficients of M = I + A for one node. c[(ry+1)*3+(rx+1)] is the
// coefficient toward target offset (ry,rx); zeroed when the TARGET node falls
// off-grid (matches reference `valid` masking on the column node).
__device__ __forceinline__ void node_coefs(const float* __restrict__ kap,
                                           const float* __restrict__ m,
                                           const float* __restrict__ H,
                                           const float* __restrict__ tau,
                                           int b, int node, int tc,
                                           int iy, int ix,
                                           float* c /*[9]*/, float& w) {
    const int base = node * NT + tc;                 // [.., node, t] layout, last dim NT
    const float kp  = kap[(b * NN) * NT + base];
    const float m1  = m[((b * 2 + 0) * NN) * NT + base];
    const float m2  = m[((b * 2 + 1) * NN) * NT + base];
    const float h11 = H[((b * 4 + 0) * NN) * NT + base];
    const float h12 = H[((b * 4 + 1) * NN) * NT + base];
    const float h22 = H[((b * 4 + 3) * NN) * NT + base];
    const float tv  = tau[(b * NN) * NT + base];
    w = 1.0f / (tv * tv);

    const float cxy = 0.5f * h12;
    const bool ym = iy > 0, yp = iy < NY - 1;
    const bool xm = ix > 0, xp = ix < NX - 1;

    c[4] = 1.0f + kp * kp + 2.0f * h11 + 2.0f * h22;
    c[0] = (ym && xm) ? -cxy               : 0.0f;
    c[1] =  ym        ? (-h22 - 0.5f * m2) : 0.0f;
    c[2] = (ym && xp) ?  cxy               : 0.0f;
    c[3] =  xm        ? (-h11 - 0.5f * m1) : 0.0f;
    c[5] =  xp        ? (-h11 + 0.5f * m1) : 0.0f;
    c[6] = (yp && xm) ?  cxy               : 0.0f;
    c[7] =  yp        ? (-h22 + 0.5f * m2) : 0.0f;
    c[8] = (yp && xp) ? -cxy               : 0.0f;
}

// Fused kernel, 16 j's per block (half a grid row at one (b,t)).
// Phase 0: stencil coefs for the 3x18 neighborhood nodes (54 nodes).
// Phase 1: the 688 nonzero values (16 j x (25 D + 9 L + 9 U)).
// Phase 2: stream out 48 coalesced float4 stores per thread (192 KB/block):
//   D[t] rows, L[t] rows (zeros when t==0), U[t-1] rows (t>=1; t==0 block
//   writes the all-zero U[7] rows instead, so coverage is exact).
__global__ __launch_bounds__(256) void spde_fused(const float* __restrict__ kap,
                                                  const float* __restrict__ m,
                                                  const float* __restrict__ H,
                                                  const float* __restrict__ tau,
                                                  float* __restrict__ out) {
    __shared__ float sc[3][18][9];   // coefs of node (jy-1+ly, jx0-1+lx)
    __shared__ float sw[3][18];      // w_t at those nodes (0 off-grid)
    __shared__ float valsD[16][25];
    __shared__ float valsL[16][9];
    __shared__ float valsU[16][9];

    const int gb   = blockIdx.x;         // b*512 + t*64 + jy*2 + half
    const int half = gb & 1;
    const int jy   = (gb >> 1) & 31;
    const int t    = (gb >> 6) & 7;
    const int b    = gb >> 9;
    const int jx0  = half * 16;
    const int tid  = threadIdx.x;

    if (tid < 54) {   // phase 0
        const int ly = tid / 18, lx = tid % 18;
        const int iy = jy + ly - 1, ix = jx0 + lx - 1;
        float c[9];
        float w = 0.0f;
        if (iy >= 0 && iy < NY && ix >= 0 && ix < NX) {
            node_coefs(kap, m, H, tau, b, iy * NX + ix, t, iy, ix, c, w);
        } else {
            #pragma unroll
            for (int q = 0; q < 9; ++q) c[q] = 0.0f;
        }
        #pragma unroll
        for (int q = 0; q < 9; ++q) sc[ly][lx][q] = c[q];
        sw[ly][lx] = w;
    }
    __syncthreads();

    // phase 1: 688 values over 256 threads (<=3 each)
    #pragma unroll
    for (int pass = 0; pass < 3; ++pass) {
        const int e = tid + pass * 256;
        if (e < 400) {                       // D: sum_i w[i] M[i,j] M[i,k]
            const int jj = e / 25, l = e % 25;
            const int dy = l / 5 - 2, dx = l % 5 - 2;
            float acc = 0.0f;
            #pragma unroll
            for (int d = 0; d < 9; ++d) {    // rows i = j + off_d
                const int ey = d / 3 - 1, ex = d % 3 - 1;
                const int r2y = dy - ey, r2x = dx - ex;
                if (r2y >= -1 && r2y <= 1 && r2x >= -1 && r2x <= 1) {
                    const float* ci = sc[ey + 1][jj + 1 + ex];
                    acc += sw[ey + 1][jj + 1 + ex] * ci[8 - d]
                                                   * ci[(r2y + 1) * 3 + (r2x + 1)];
                }
            }
            if (l == 12 && t < NT - 1) {     // diagonal: + w_{t+1}[j]
                const int j = jy * NX + jx0 + jj;
                const float tv = tau[((size_t)b * NN + j) * NT + (t + 1)];
                acc += 1.0f / (tv * tv);
            }
            valsD[jj][l] = acc;
        } else if (e < 544) {                // L: -w_t[k] M_t[k,j], k=j+off_d
            const int e2 = e - 400;
            const int jj = e2 / 9, d = e2 % 9;
            const int ey = d / 3 - 1, ex = d % 3 - 1;
            valsL[jj][d] = -sw[ey + 1][jj + 1 + ex] * sc[ey + 1][jj + 1 + ex][8 - d];
        } else if (e < 688) {                // U: -w_t[j] M_t[j,k]
            const int e2 = e - 544;
            const int jj = e2 / 9, qi = e2 % 9;
            valsU[jj][qi] = -sw[1][jj + 1] * sc[1][jj + 1][qi];
        }
    }
    __syncthreads();

    // phase 2: 48 coalesced float4 stores per thread
    const int q   = tid;                 // quad index within a 1024-float row
    const int ky  = q >> 3, kx0 = (q & 7) * 4;
    const int ddy = ky - jy;             // same for all 16 j's in this block
    float4* const outq = (float4*)out;
    const size_t matD = ((size_t)(b * 3 + 0) * NT + t) << 18;   // quads per matrix
    const size_t matL = ((size_t)(b * 3 + 1) * NT + t) << 18;
    const int ut = (t >= 1) ? (t - 1) : 7;
    const size_t matU = ((size_t)(b * 3 + 2) * NT + ut) << 18;
    const bool inD  = (ddy >= -2 && ddy <= 2);
    const bool inLU = (ddy >= -1 && ddy <= 1);

    #pragma unroll 4
    for (int jj = 0; jj < 16; ++jj) {
        const int jx = jx0 + jj;
        const int j  = jy * NX + jx;
        const size_t rq = ((size_t)j << 8) + q;
        float4 vD = make_float4(0.f, 0.f, 0.f, 0.f);
        float4 vL = make_float4(0.f, 0.f, 0.f, 0.f);
        float4 vU = make_float4(0.f, 0.f, 0.f, 0.f);
        if (inD) {
            float* vp = &vD.x;
            const float* wrow = &valsD[jj][(ddy + 2) * 5 + 2];
            #pragma unroll
            for (int qq = 0; qq < 4; ++qq) {
                const int ddx = kx0 + qq - jx;
                if (ddx >= -2 && ddx <= 2) vp[qq] = wrow[ddx];
            }
        }
        if (inLU) {
            if (t > 0) {
                float* vp = &vL.x;
                const float* wrow = &valsL[jj][(ddy + 1) * 3 + 1];
                #pragma unroll
                for (int qq = 0; qq < 4; ++qq) {
                    const int ddx = kx0 + qq - jx;
                    if (ddx >= -1 && ddx <= 1) vp[qq] = wrow[ddx];
                }
            }
            if (t >= 1) {
                float* vp = &vU.x;
                const float* wrow = &valsU[jj][(ddy + 1) * 3 + 1];
                #pragma unroll
                for (int qq = 0; qq < 4; ++qq) {
                    const int ddx = kx0 + qq - jx;
                    if (ddx >= -1 && ddx <= 1) vp[qq] = wrow[ddx];
                }
            }
        }
        outq[matD + rq] = vD;
        outq[matL + rq] = vL;
        outq[matU + rq] = vU;
    }
}

extern "C" void kernel_launch(void* const* d_in, const int* in_sizes, int n_in,
                              void* d_out, int out_size, void* d_ws, size_t ws_size,
                              hipStream_t stream) {
    (void)n_in; (void)d_ws; (void)ws_size; (void)out_size;
    const float* kap = (const float*)d_in[0];  // [n_b,1,N,NT]
    const float* m   = (const float*)d_in[1];  // [n_b,2,N,NT]
    const float* H   = (const float*)d_in[2];  // [n_b,2,2,N,NT]
    const float* tau = (const float*)d_in[3];  // [n_b,1,N,NT]
    float* out = (float*)d_out;                // [n_b,3,NT,N,N]

    const int n_b = in_sizes[0] / (NN * NT);
    const int grid = n_b * NT * NY * 2;        // one block per (b,t,jy,half-row)
    spde_fused<<<grid, 256, 0, stream>>>(kap, m, H, tau, out);
}

// Round 3
// 194.456 us; speedup vs baseline: 1.0643x; 1.0362x over previous
//
#include <hip/hip_runtime.h>

#define NT 8
#define NY 32
#define NX 32
#define NN 1024  // NY*NX

// Stencil coefficients of M = I + A for one node. c[(ry+1)*3+(rx+1)] is the
// coefficient toward target offset (ry,rx); zeroed when the TARGET node falls
// off-grid (matches reference `valid` masking on the column node).
__device__ __forceinline__ void node_coefs(const float* __restrict__ kap,
                                           const float* __restrict__ m,
                                           const float* __restrict__ H,
                                           const float* __restrict__ tau,
                                           int b, int node, int tc,
                                           int iy, int ix,
                                           float* c /*[9]*/, float& w) {
    const int base = node * NT + tc;                 // [.., node, t] layout, last dim NT
    const float kp  = kap[(b * NN) * NT + base];
    const float m1  = m[((b * 2 + 0) * NN) * NT + base];
    const float m2  = m[((b * 2 + 1) * NN) * NT + base];
    const float h11 = H[((b * 4 + 0) * NN) * NT + base];
    const float h12 = H[((b * 4 + 1) * NN) * NT + base];
    const float h22 = H[((b * 4 + 3) * NN) * NT + base];
    const float tv  = tau[(b * NN) * NT + base];
    w = 1.0f / (tv * tv);

    const float cxy = 0.5f * h12;
    const bool ym = iy > 0, yp = iy < NY - 1;
    const bool xm = ix > 0, xp = ix < NX - 1;

    c[4] = 1.0f + kp * kp + 2.0f * h11 + 2.0f * h22;
    c[0] = (ym && xm) ? -cxy               : 0.0f;
    c[1] =  ym        ? (-h22 - 0.5f * m2) : 0.0f;
    c[2] = (ym && xp) ?  cxy               : 0.0f;
    c[3] =  xm        ? (-h11 - 0.5f * m1) : 0.0f;
    c[5] =  xp        ? (-h11 + 0.5f * m1) : 0.0f;
    c[6] = (yp && xm) ?  cxy               : 0.0f;
    c[7] =  yp        ? (-h22 + 0.5f * m2) : 0.0f;
    c[8] = (yp && xp) ? -cxy               : 0.0f;
}

// Scatter kernel over a pre-zeroed output. 2 j's per 256-thread block,
// 128 threads per j. Writes ONLY whole 128B "ky segments" (32 floats,
// cols 0..31 of one grid row ky, within the j-th matrix row):
//   D[t]   : ky = jy-2..jy+2   (5 segments)
//   L[t]   : ky = jy-1..jy+1   (3 segments, t>=1; L[0] stays memset-zero)
//   U[t-1] : ky = jy-1..jy+1   (3 segments, t>=1; U[7] stays memset-zero)
// Each segment is written by 8 consecutive lanes (float4 each) -> full
// 64B-line stores, no read-modify-write.
__global__ __launch_bounds__(256) void spde_scatter(const float* __restrict__ kap,
                                                    const float* __restrict__ m,
                                                    const float* __restrict__ H,
                                                    const float* __restrict__ tau,
                                                    float* __restrict__ out) {
    __shared__ float sc[2][9][9];   // sc[jj][d][r]: coef of node j+off_d toward offset r
    __shared__ float sw[2][9];      // w_t at node j+off_d (0 if off-grid)
    __shared__ float valsD[2][25];
    __shared__ float valsL[2][9];
    __shared__ float valsU[2][9];

    const int gb   = blockIdx.x;        // ((b*NT)+t)*512 + jpair ; j = jpair*2 + jj
    const int jp   = gb & 511;
    const int bt   = gb >> 9;
    const int t    = bt & 7;
    const int b    = bt >> 3;
    const int tid  = threadIdx.x;
    const int jj   = tid >> 7;          // which j this 128-thread group owns
    const int g    = tid & 127;         // lane within the j-group
    const int j    = jp * 2 + jj;
    const int jy   = j >> 5, jx = j & 31;

    if (g < 9) {  // phase A: stencil coefs of the 9 neighborhood nodes at time t
        const int ey = g / 3 - 1, ex = g % 3 - 1;
        const int iy = jy + ey, ix = jx + ex;
        float c[9];
        float w = 0.0f;
        if (iy >= 0 && iy < NY && ix >= 0 && ix < NX) {
            node_coefs(kap, m, H, tau, b, iy * NX + ix, t, iy, ix, c, w);
        } else {
            #pragma unroll
            for (int q = 0; q < 9; ++q) c[q] = 0.0f;
        }
        #pragma unroll
        for (int q = 0; q < 9; ++q) sc[jj][g][q] = c[q];
        sw[jj][g] = w;
    }
    __syncthreads();

    if (g < 25) {                     // phase B: D values
        const int dy = g / 5 - 2, dx = g % 5 - 2;
        float acc = 0.0f;
        #pragma unroll
        for (int d = 0; d < 9; ++d) {   // rows i = j + off_d
            const int ey = d / 3 - 1, ex = d % 3 - 1;
            const int r2y = dy - ey, r2x = dx - ex;
            if (r2y >= -1 && r2y <= 1 && r2x >= -1 && r2x <= 1) {
                acc += sw[jj][d] * sc[jj][d][8 - d]
                                 * sc[jj][d][(r2y + 1) * 3 + (r2x + 1)];
            }
        }
        if (g == 12 && t < NT - 1) {    // diagonal: + w_{t+1}[j]
            const float tv = tau[((size_t)b * NN + j) * NT + (t + 1)];
            acc += 1.0f / (tv * tv);
        }
        valsD[jj][g] = acc;
    } else if (g >= 32 && g < 41) {   // lower[t]: -w_t[k] M_t[k,j]
        const int d = g - 32;
        valsL[jj][d] = -sw[jj][d] * sc[jj][d][8 - d];
    } else if (g >= 48 && g < 57) {   // upper[t-1]: -w_t[j] M_t[j,k]
        const int q = g - 48;
        valsU[jj][q] = -sw[jj][4] * sc[jj][4][q];
    }
    __syncthreads();

    // phase C: full-segment stores. s = segment role, q = quad within segment.
    if (g < 88) {
        const int s = g >> 3, q = g & 7;
        float4* const outq = (float4*)out;
        float4 v = make_float4(0.f, 0.f, 0.f, 0.f);
        float* vp = &v.x;

        if (s < 5) {                                   // D segments
            const int dy = s - 2, ky = jy + dy;
            if (ky >= 0 && ky < NY) {
                #pragma unroll
                for (int c = 0; c < 4; ++c) {
                    const int ddx = q * 4 + c - jx;
                    if (ddx >= -2 && ddx <= 2) vp[c] = valsD[jj][(dy + 2) * 5 + (ddx + 2)];
                }
                const size_t matD = ((size_t)(b * 3 + 0) * NT + t) << 18;
                outq[matD + ((size_t)j << 8) + ky * 8 + q] = v;
            }
        } else if (s < 8) {                            // L segments (t>=1)
            const int dy = s - 6, ky = jy + dy;
            if (t > 0 && ky >= 0 && ky < NY) {
                #pragma unroll
                for (int c = 0; c < 4; ++c) {
                    const int ddx = q * 4 + c - jx;
                    if (ddx >= -1 && ddx <= 1) vp[c] = valsL[jj][(dy + 1) * 3 + (ddx + 1)];
                }
                const size_t matL = ((size_t)(b * 3 + 1) * NT + t) << 18;
                outq[matL + ((size_t)j << 8) + ky * 8 + q] = v;
            }
        } else {                                       // U segments (t>=1), matrix t-1
            const int dy = s - 9, ky = jy + dy;
            if (t > 0 && ky >= 0 && ky < NY) {
                #pragma unroll
                for (int c = 0; c < 4; ++c) {
                    const int ddx = q * 4 + c - jx;
                    if (ddx >= -1 && ddx <= 1) vp[c] = valsU[jj][(dy + 1) * 3 + (ddx + 1)];
                }
                const size_t matU = ((size_t)(b * 3 + 2) * NT + (t - 1)) << 18;
                outq[matU + ((size_t)j << 8) + ky * 8 + q] = v;
            }
        }
    }
}

extern "C" void kernel_launch(void* const* d_in, const int* in_sizes, int n_in,
                              void* d_out, int out_size, void* d_ws, size_t ws_size,
                              hipStream_t stream) {
    (void)n_in; (void)d_ws; (void)ws_size;
    const float* kap = (const float*)d_in[0];  // [n_b,1,N,NT]
    const float* m   = (const float*)d_in[1];  // [n_b,2,N,NT]
    const float* H   = (const float*)d_in[2];  // [n_b,2,2,N,NT]
    const float* tau = (const float*)d_in[3];  // [n_b,1,N,NT]
    float* out = (float*)d_out;                // [n_b,3,NT,N,N]

    const int n_b = in_sizes[0] / (NN * NT);

    // Phase 1: zero the whole output via the vendor fill path (~6.7 TB/s measured).
    hipMemsetAsync(d_out, 0, (size_t)out_size, stream);

    // Phase 2: full-line segment scatter of the nonzeros.
    const int grid = n_b * NT * (NN / 2);      // 2 j's per block
    spde_scatter<<<grid, 256, 0, stream>>>(kap, m, H, tau, out);
}